// Round 8
// baseline (916.624 us; speedup 1.0000x reference)
//
#include <hip/hip_runtime.h>
#include <cstdint>
#include <cstddef>

#define NFEAT 128
#define TGRAPH 10
#define NGRAPHS 512
#define BN_EPS 1e-5f
#define BIN_CHUNK 2048

typedef __attribute__((ext_vector_type(8))) short bf16x8;
typedef __attribute__((ext_vector_type(4))) float f32x4;

__device__ __forceinline__ float bf2f(short s) {
    union { unsigned u; float f; } c;
    c.u = ((unsigned)(unsigned short)s) << 16;
    return c.f;
}
__device__ __forceinline__ short f2bf(float f) {
    union { float f; unsigned u; } c;
    c.f = f;
    unsigned u = c.u;
    return (short)((u + 0x7fffu + ((u >> 16) & 1u)) >> 16);
}

// ---------------- CSR build, bucket-local (bucket = dst>>9, <=256 buckets) ----------------
__global__ __launch_bounds__(256) void k_bucket_hist(const int* __restrict__ dst,
                                                     int* __restrict__ bhist, int E) {
    __shared__ int h[256];
    int t = threadIdx.x;
    h[t] = 0;
    __syncthreads();
    for (int e = blockIdx.x * blockDim.x + t; e < E; e += gridDim.x * blockDim.x)
        atomicAdd(&h[dst[e] >> 9], 1);
    __syncthreads();
    if (h[t]) atomicAdd(&bhist[t], h[t]);
}

__global__ void k_bucket_scan(const int* __restrict__ bhist, int* __restrict__ bbase,
                              int* __restrict__ cur256, int E) {
    __shared__ int s[256];
    int t = threadIdx.x;
    int v = bhist[t];
    s[t] = v;
    __syncthreads();
    for (int off = 1; off < 256; off <<= 1) {
        int x = 0;
        if (t >= off) x = s[t - off];
        __syncthreads();
        if (t >= off) s[t] += x;
        __syncthreads();
    }
    int excl = s[t] - v;
    bbase[t] = excl;
    cur256[t] = excl;
    if (t == 255) bbase[256] = E;
}

__global__ __launch_bounds__(256) void k_bin_scatter(const int* __restrict__ src,
                                                     const int* __restrict__ dst,
                                                     int* __restrict__ cur256,
                                                     int2* __restrict__ binned, int E) {
    __shared__ int hist[256];
    __shared__ int base[256];
    int t = threadIdx.x;
    int e0 = blockIdx.x * BIN_CHUNK;
    int e1 = min(e0 + BIN_CHUNK, E);
    hist[t] = 0;
    __syncthreads();
    for (int e = e0 + t; e < e1; e += 256) {
        int b = dst[e] >> 9;
        atomicAdd(&hist[b], 1);
    }
    __syncthreads();
    int c = hist[t];
    if (c > 0) base[t] = atomicAdd(&cur256[t], c);
    __syncthreads();
    hist[t] = 0;
    __syncthreads();
    for (int e = e0 + t; e < e1; e += 256) {
        int d = dst[e];
        int b = d >> 9;
        int loc = atomicAdd(&hist[b], 1);
        binned[base[b] + loc] = make_int2(src[e], d);
    }
}

__global__ __launch_bounds__(512) void k_bucket_csr(const int2* __restrict__ binned,
                                                    const int* __restrict__ bbase,
                                                    int* __restrict__ rowptr,
                                                    int* __restrict__ adj,
                                                    int N, int E, int nb) {
    __shared__ int deg[512];
    __shared__ int cur[512];
    int b = blockIdx.x;
    int t = threadIdx.x;
    int e0 = bbase[b], e1 = bbase[b + 1];
    deg[t] = 0;
    __syncthreads();
    for (int e = e0 + t; e < e1; e += 512)
        atomicAdd(&deg[binned[e].y & 511], 1);
    __syncthreads();
    int v = deg[t];
    for (int off = 1; off < 512; off <<= 1) {
        int x = 0;
        if (t >= off) x = deg[t - off];
        __syncthreads();
        if (t >= off) deg[t] += x;
        __syncthreads();
    }
    int excl = deg[t] - v;
    cur[t] = excl;
    int node = b * 512 + t;
    if (node < N) rowptr[node] = e0 + excl;
    if (b == nb - 1 && t == 0) rowptr[N] = E;
    __syncthreads();
    for (int e = e0 + t; e < e1; e += 512) {
        int2 p = binned[e];
        int loc = atomicAdd(&cur[p.y & 511], 1);
        adj[e0 + loc] = p.x;
    }
}

// ---------------- fused fp32->bf16 convert (x) + weight frag prep ----------------
__global__ void k_prep(const float* __restrict__ x, short* __restrict__ xbf,
                       const float* __restrict__ W0, const float* __restrict__ W1,
                       const float* __restrict__ W2, const float* __restrict__ W3,
                       short* __restrict__ Wf, int n4) {
    int i = blockIdx.x * blockDim.x + threadIdx.x;
    if (i < n4) {
        float4 v = ((const float4*)x)[i];
        ushort4 o;
        o.x = (unsigned short)f2bf(v.x);
        o.y = (unsigned short)f2bf(v.y);
        o.z = (unsigned short)f2bf(v.z);
        o.w = (unsigned short)f2bf(v.w);
        ((ushort4*)xbf)[i] = o;
    } else {
        int idx = i - n4;
        if (idx < 4 * 16384) {
            int w = idx >> 14, r = idx & 16383;
            int j = r & 7, lane = (r >> 3) & 63, ct = (r >> 9) & 7, kc = r >> 12;
            int k = kc * 32 + (lane >> 4) * 8 + j;
            int n = ct * 16 + (lane & 15);
            const float* W = (w == 0) ? W0 : (w == 1) ? W1 : (w == 2) ? W2 : W3;
            Wf[idx] = f2bf(W[k * NFEAT + n]);
        }
    }
}

// ---------------- aggregation, feature-sliced & XCD-aligned ----------------
// slice = blockIdx%8 (round-robin block->XCD heuristic): each XCD gathers only its
// 16-feature slice (100k x 32B = 3.2MB) -> fits its 4MB L2 -> gathers become L2 hits.
// Wave layout: lane = slot*8 + d; slot = edge slot (8 edges/iter), d = dword in 32B slice.
// Cross-slot reduction via 3-step shfl_xor; lanes 0..7 add self row and store.
__global__ __launch_bounds__(256) void k_aggregate_sl(const short* __restrict__ X,
                                                      const int* __restrict__ rowptr,
                                                      const int* __restrict__ adj,
                                                      short* __restrict__ XA, int N) {
    int tid = threadIdx.x;
    int lane = tid & 63;
    int slot = lane >> 3;
    int d = lane & 7;
    int slice = blockIdx.x & 7;
    int sliceByte = slice * 32 + d * 4;
    int wid = (blockIdx.x >> 3) * 4 + (tid >> 6);
    int nw = (gridDim.x >> 3) * 4;
    const char* Xb = (const char*)X;
    for (int n = wid; n < N; n += nw) {
        int r0 = rowptr[n], r1 = rowptr[n + 1];
        float ax = 0.f, ay = 0.f;
        for (int e = r0; e < r1; e += 8) {
            int ee = e + slot;
            unsigned v = 0;
            if (ee < r1) {
                int srow = adj[ee];
                v = *(const unsigned*)(Xb + (size_t)srow * 256 + sliceByte);
            }
            ax += bf2f((short)(v & 0xffff));
            ay += bf2f((short)(v >> 16));
        }
        ax += __shfl_xor(ax, 8);
        ay += __shfl_xor(ay, 8);
        ax += __shfl_xor(ax, 16);
        ay += __shfl_xor(ay, 16);
        ax += __shfl_xor(ax, 32);
        ay += __shfl_xor(ay, 32);
        if (slot == 0) {
            unsigned sv = *(const unsigned*)(Xb + (size_t)n * 256 + sliceByte);
            ax += bf2f((short)(sv & 0xffff));
            ay += bf2f((short)(sv >> 16));
            unsigned o = (unsigned)(unsigned short)f2bf(ax) |
                         ((unsigned)(unsigned short)f2bf(ay) << 16);
            *(unsigned*)((char*)XA + (size_t)n * 256 + sliceByte) = o;
        }
    }
}

// ---------------- MFMA GEMM (+optional fused BN col-stats) ----------------
template <bool BN_RELU_IN, bool RELU_OUT, bool STATS>
__global__ __launch_bounds__(256) void k_gemm_mfma(const short* __restrict__ A,
                                                   const short* __restrict__ Wf,
                                                   const float* __restrict__ bias,
                                                   const float* __restrict__ scale,
                                                   const float* __restrict__ shift,
                                                   float* __restrict__ stats,
                                                   short* __restrict__ C, int N) {
    __shared__ float s_sum[NFEAT];
    __shared__ float s_sq[NFEAT];
    int tid = threadIdx.x;
    int wave = tid >> 6, lane = tid & 63;
    int quad = lane >> 4, l16 = lane & 15;
    int row_base = blockIdx.x * 128 + wave * 32;

    if constexpr (STATS) {
        if (tid < NFEAT) { s_sum[tid] = 0.f; s_sq[tid] = 0.f; }
        __syncthreads();
    }

    f32x4 acc[2][8];
#pragma unroll
    for (int i = 0; i < 2; i++)
#pragma unroll
        for (int j = 0; j < 8; j++) acc[i][j] = (f32x4){0.f, 0.f, 0.f, 0.f};

    int r0 = row_base + l16;
    int r1 = r0 + 16;

#pragma unroll
    for (int kc = 0; kc < 4; ++kc) {
        int koff = kc * 32 + quad * 8;
        bf16x8 a0 = {}, a1 = {};
        if (r0 < N) a0 = *(const bf16x8*)(A + (size_t)r0 * NFEAT + koff);
        if (r1 < N) a1 = *(const bf16x8*)(A + (size_t)r1 * NFEAT + koff);
        if constexpr (BN_RELU_IN) {
            float sc[8], sh[8];
            *(float4*)(sc) = *(const float4*)(scale + koff);
            *(float4*)(sc + 4) = *(const float4*)(scale + koff + 4);
            *(float4*)(sh) = *(const float4*)(shift + koff);
            *(float4*)(sh + 4) = *(const float4*)(shift + koff + 4);
#pragma unroll
            for (int j = 0; j < 8; j++) {
                float v = fmaxf(bf2f(a0[j]) * sc[j] + sh[j], 0.f);
                float u = fmaxf(bf2f(a1[j]) * sc[j] + sh[j], 0.f);
                a0[j] = f2bf(v);
                a1[j] = f2bf(u);
            }
        }
        const short* wp = Wf + ((size_t)(kc * 8) * 64 + lane) * 8;
#pragma unroll
        for (int ct = 0; ct < 8; ++ct) {
            bf16x8 b = *(const bf16x8*)(wp + (size_t)ct * 64 * 8);
            acc[0][ct] = __builtin_amdgcn_mfma_f32_16x16x32_bf16(a0, b, acc[0][ct], 0, 0, 0);
            acc[1][ct] = __builtin_amdgcn_mfma_f32_16x16x32_bf16(a1, b, acc[1][ct], 0, 0, 0);
        }
    }

    // C/D layout: col = lane&15, row = quad*4 + reg
#pragma unroll
    for (int ct = 0; ct < 8; ++ct) {
        int col = ct * 16 + l16;
        float bv = bias[col];
        float ls = 0.f, ls2 = 0.f;
#pragma unroll
        for (int rt = 0; rt < 2; ++rt) {
#pragma unroll
            for (int reg = 0; reg < 4; ++reg) {
                int row = row_base + rt * 16 + quad * 4 + reg;
                if (row < N) {
                    float v = acc[rt][ct][reg] + bv;
                    if constexpr (RELU_OUT) v = fmaxf(v, 0.f);
                    C[(size_t)row * NFEAT + col] = f2bf(v);
                    if constexpr (STATS) { ls += v; ls2 += v * v; }
                }
            }
        }
        if constexpr (STATS) {
            atomicAdd(&s_sum[col], ls);
            atomicAdd(&s_sq[col], ls2);
        }
    }

    if constexpr (STATS) {
        __syncthreads();
        if (tid < NFEAT) {
            atomicAdd(&stats[tid], s_sum[tid]);
            atomicAdd(&stats[NFEAT + tid], s_sq[tid]);
        }
    }
}

__global__ void k_bnfinalize(const float* __restrict__ stats, const float* __restrict__ gamma,
                             const float* __restrict__ beta, float* __restrict__ scale,
                             float* __restrict__ shift, int N) {
    int c = threadIdx.x;
    if (c < NFEAT) {
        float mean = stats[c] / (float)N;
        float var = stats[NFEAT + c] / (float)N - mean * mean;
        float inv = rsqrtf(var + BN_EPS);
        float sc = gamma[c] * inv;
        scale[c] = sc;
        shift[c] = beta[c] - mean * sc;
    }
}

// ---------------- node-parallel pooling (batch sorted; per-run register accum) ----------
__global__ __launch_bounds__(256) void k_pool2(const short* __restrict__ H2,
                                               const int* __restrict__ batch,
                                               float* __restrict__ pooled, int N) {
    int t = threadIdx.x;
    int c2 = t & 63;
    int rofs = t >> 6;
    int n0 = blockIdx.x * 128;
    int cur = -1;
    float ax = 0.f, ay = 0.f;
    for (int i = 0; i < 32; ++i) {
        int n = n0 + rofs + i * 4;
        if (n >= N) break;
        int g = batch[n];
        if (g != cur) {
            if (cur >= 0) {
                atomicAdd(&pooled[cur * NFEAT + c2 * 2], ax);
                atomicAdd(&pooled[cur * NFEAT + c2 * 2 + 1], ay);
            }
            cur = g; ax = 0.f; ay = 0.f;
        }
        unsigned v = *(const unsigned*)(H2 + (size_t)n * NFEAT + c2 * 2);
        ax += bf2f((short)(v & 0xffff));
        ay += bf2f((short)(v >> 16));
    }
    if (cur >= 0) {
        atomicAdd(&pooled[cur * NFEAT + c2 * 2], ax);
        atomicAdd(&pooled[cur * NFEAT + c2 * 2 + 1], ay);
    }
}

__global__ void k_final(const float* __restrict__ pooled, const float* __restrict__ Wl,
                        const float* __restrict__ bl, float* __restrict__ out) {
    int idx = blockIdx.x * blockDim.x + threadIdx.x;
    if (idx >= NGRAPHS * TGRAPH) return;
    int g = idx / TGRAPH, t = idx % TGRAPH;
    const float* p = pooled + (size_t)g * NFEAT;
    float acc = bl[t];
#pragma unroll 16
    for (int k = 0; k < NFEAT; ++k) acc += p[k] * Wl[k * TGRAPH + t];
    out[idx] = acc;
}

extern "C" void kernel_launch(void* const* d_in, const int* in_sizes, int n_in,
                              void* d_out, int out_size, void* d_ws, size_t ws_size,
                              hipStream_t stream) {
    const float* x = (const float*)d_in[0];
    const int* ei = (const int*)d_in[1];
    const int* batch = (const int*)d_in[2];
    const float* W1a = (const float*)d_in[3];
    const float* b1a = (const float*)d_in[4];
    const float* g1 = (const float*)d_in[5];
    const float* bt1 = (const float*)d_in[6];
    const float* W1b = (const float*)d_in[7];
    const float* b1b = (const float*)d_in[8];
    const float* W2a = (const float*)d_in[9];
    const float* b2a = (const float*)d_in[10];
    const float* g2 = (const float*)d_in[11];
    const float* bt2 = (const float*)d_in[12];
    const float* W2b = (const float*)d_in[13];
    const float* b2b = (const float*)d_in[14];
    const float* Wl = (const float*)d_in[15];
    const float* bl = (const float*)d_in[16];
    float* out = (float*)d_out;

    int N = in_sizes[2];
    int E = in_sizes[1] / 2;
    int nb = (N + 511) >> 9;
    const int* src = ei;
    const int* dst = ei + E;

    char* ws = (char*)d_ws;
    size_t off = 0;
    auto alloc = [&](size_t bytes) -> void* {
        void* p = ws + off;
        off = (off + bytes + 255) & ~(size_t)255;
        return p;
    };
    short* xbf = (short*)alloc((size_t)N * NFEAT * 2);
    short* ag = (short*)alloc((size_t)N * NFEAT * 2);
    short* ybf = (short*)alloc((size_t)N * NFEAT * 2);
    short* hbf = (short*)alloc((size_t)N * NFEAT * 2);
    short* h2bf = (short*)alloc((size_t)N * NFEAT * 2);
    short* Wf = (short*)alloc((size_t)4 * 16384 * 2);
    int* adj = (int*)alloc((size_t)E * 4);
    int2* binned = (int2*)alloc((size_t)E * 8);
    int* rowptr = (int*)alloc((size_t)(N + 1) * 4);
    int* bbase = (int*)alloc(257 * 4);
    int* cur256 = (int*)alloc(256 * 4);
    float* scale = (float*)alloc(128 * 4);
    float* shift = (float*)alloc(128 * 4);
    int* bhist = (int*)alloc(256 * 4);
    float* stats1 = (float*)alloc(256 * 4);
    float* stats2 = (float*)alloc(256 * 4);
    float* pooled = (float*)alloc((size_t)NGRAPHS * NFEAT * 4);
    size_t zbytes = (char*)(pooled + (size_t)NGRAPHS * NFEAT) - (char*)bhist;

    hipMemsetAsync(bhist, 0, zbytes, stream);

    // ---- CSR build (bucket-local) ----
    k_bucket_hist<<<784, 256, 0, stream>>>(dst, bhist, E);
    k_bucket_scan<<<1, 256, 0, stream>>>(bhist, bbase, cur256, E);
    k_bin_scatter<<<(E + BIN_CHUNK - 1) / BIN_CHUNK, 256, 0, stream>>>(src, dst, cur256, binned, E);
    k_bucket_csr<<<nb, 512, 0, stream>>>(binned, bbase, rowptr, adj, N, E, nb);

    // ---- dtype prep (fused) ----
    int n4 = N * NFEAT / 4;
    int prepTot = n4 + 4 * 16384;
    k_prep<<<(prepTot + 255) / 256, 256, 0, stream>>>(x, xbf, W1a, W1b, W2a, W2b, Wf, n4);

    int gemmBlocks = (N + 127) / 128;
    int aggBlocks = 8 * 512;  // 8 slices x 512 blocks

    // ---- layer 1 ----
    k_aggregate_sl<<<aggBlocks, 256, 0, stream>>>(xbf, rowptr, adj, ag, N);
    k_gemm_mfma<false, false, true><<<gemmBlocks, 256, 0, stream>>>(ag, Wf + 0 * 16384, b1a, nullptr, nullptr, stats1, ybf, N);
    k_bnfinalize<<<1, 128, 0, stream>>>(stats1, g1, bt1, scale, shift, N);
    k_gemm_mfma<true, true, false><<<gemmBlocks, 256, 0, stream>>>(ybf, Wf + 1 * 16384, b1b, scale, shift, nullptr, hbf, N);

    // ---- layer 2 ----
    k_aggregate_sl<<<aggBlocks, 256, 0, stream>>>(hbf, rowptr, adj, ag, N);
    k_gemm_mfma<false, false, true><<<gemmBlocks, 256, 0, stream>>>(ag, Wf + 2 * 16384, b2a, nullptr, nullptr, stats2, ybf, N);
    k_bnfinalize<<<1, 128, 0, stream>>>(stats2, g2, bt2, scale, shift, N);
    k_gemm_mfma<true, true, false><<<gemmBlocks, 256, 0, stream>>>(ybf, Wf + 3 * 16384, b2b, scale, shift, nullptr, h2bf, N);

    // ---- pooling + classifier ----
    k_pool2<<<(N + 127) / 128, 256, 0, stream>>>(h2bf, batch, pooled, N);
    k_final<<<(NGRAPHS * TGRAPH + 255) / 256, 256, 0, stream>>>(pooled, Wl, bl, out);
}

// Round 9
// 530.641 us; speedup vs baseline: 1.7274x; 1.7274x over previous
//
#include <hip/hip_runtime.h>
#include <cstdint>
#include <cstddef>

#define NFEAT 128
#define TGRAPH 10
#define NGRAPHS 512
#define BN_EPS 1e-5f
#define BIN_CHUNK 2048

typedef __attribute__((ext_vector_type(8))) short bf16x8;
typedef __attribute__((ext_vector_type(4))) float f32x4;

__device__ __forceinline__ float bf2f(short s) {
    union { unsigned u; float f; } c;
    c.u = ((unsigned)(unsigned short)s) << 16;
    return c.f;
}
__device__ __forceinline__ short f2bf(float f) {
    union { float f; unsigned u; } c;
    c.f = f;
    unsigned u = c.u;
    return (short)((u + 0x7fffu + ((u >> 16) & 1u)) >> 16);
}
// accumulate both bf16 halves of dword v into a (low) and b (high)
__device__ __forceinline__ void acc2(float& a, float& b, unsigned v) {
    union { unsigned u; float f; } lo, hi;
    lo.u = v << 16;
    hi.u = v & 0xffff0000u;
    a += lo.f;
    b += hi.f;
}

// ---------------- CSR build, bucket-local (bucket = dst>>9, <=256 buckets) ----------------
__global__ __launch_bounds__(256) void k_bucket_hist(const int* __restrict__ dst,
                                                     int* __restrict__ bhist, int E) {
    __shared__ int h[256];
    int t = threadIdx.x;
    h[t] = 0;
    __syncthreads();
    for (int e = blockIdx.x * blockDim.x + t; e < E; e += gridDim.x * blockDim.x)
        atomicAdd(&h[dst[e] >> 9], 1);
    __syncthreads();
    if (h[t]) atomicAdd(&bhist[t], h[t]);
}

__global__ void k_bucket_scan(const int* __restrict__ bhist, int* __restrict__ bbase,
                              int* __restrict__ cur256, int E) {
    __shared__ int s[256];
    int t = threadIdx.x;
    int v = bhist[t];
    s[t] = v;
    __syncthreads();
    for (int off = 1; off < 256; off <<= 1) {
        int x = 0;
        if (t >= off) x = s[t - off];
        __syncthreads();
        if (t >= off) s[t] += x;
        __syncthreads();
    }
    int excl = s[t] - v;
    bbase[t] = excl;
    cur256[t] = excl;
    if (t == 255) bbase[256] = E;
}

__global__ __launch_bounds__(256) void k_bin_scatter(const int* __restrict__ src,
                                                     const int* __restrict__ dst,
                                                     int* __restrict__ cur256,
                                                     int2* __restrict__ binned, int E) {
    __shared__ int hist[256];
    __shared__ int base[256];
    int t = threadIdx.x;
    int e0 = blockIdx.x * BIN_CHUNK;
    int e1 = min(e0 + BIN_CHUNK, E);
    hist[t] = 0;
    __syncthreads();
    for (int e = e0 + t; e < e1; e += 256) {
        int b = dst[e] >> 9;
        atomicAdd(&hist[b], 1);
    }
    __syncthreads();
    int c = hist[t];
    if (c > 0) base[t] = atomicAdd(&cur256[t], c);
    __syncthreads();
    hist[t] = 0;
    __syncthreads();
    for (int e = e0 + t; e < e1; e += 256) {
        int d = dst[e];
        int b = d >> 9;
        int loc = atomicAdd(&hist[b], 1);
        binned[base[b] + loc] = make_int2(src[e], d);
    }
}

__global__ __launch_bounds__(512) void k_bucket_csr(const int2* __restrict__ binned,
                                                    const int* __restrict__ bbase,
                                                    int* __restrict__ rowptr,
                                                    int* __restrict__ adj,
                                                    int N, int E, int nb) {
    __shared__ int deg[512];
    __shared__ int cur[512];
    int b = blockIdx.x;
    int t = threadIdx.x;
    int e0 = bbase[b], e1 = bbase[b + 1];
    deg[t] = 0;
    __syncthreads();
    for (int e = e0 + t; e < e1; e += 512)
        atomicAdd(&deg[binned[e].y & 511], 1);
    __syncthreads();
    int v = deg[t];
    for (int off = 1; off < 512; off <<= 1) {
        int x = 0;
        if (t >= off) x = deg[t - off];
        __syncthreads();
        if (t >= off) deg[t] += x;
        __syncthreads();
    }
    int excl = deg[t] - v;
    cur[t] = excl;
    int node = b * 512 + t;
    if (node < N) rowptr[node] = e0 + excl;
    if (b == nb - 1 && t == 0) rowptr[N] = E;
    __syncthreads();
    for (int e = e0 + t; e < e1; e += 512) {
        int2 p = binned[e];
        int loc = atomicAdd(&cur[p.y & 511], 1);
        adj[e0 + loc] = p.x;
    }
}

// ---------------- fused fp32->bf16 convert (x) + weight frag prep ----------------
__global__ void k_prep(const float* __restrict__ x, short* __restrict__ xbf,
                       const float* __restrict__ W0, const float* __restrict__ W1,
                       const float* __restrict__ W2, const float* __restrict__ W3,
                       short* __restrict__ Wf, int n4) {
    int i = blockIdx.x * blockDim.x + threadIdx.x;
    if (i < n4) {
        float4 v = ((const float4*)x)[i];
        ushort4 o;
        o.x = (unsigned short)f2bf(v.x);
        o.y = (unsigned short)f2bf(v.y);
        o.z = (unsigned short)f2bf(v.z);
        o.w = (unsigned short)f2bf(v.w);
        ((ushort4*)xbf)[i] = o;
    } else {
        int idx = i - n4;
        if (idx < 4 * 16384) {
            int w = idx >> 14, r = idx & 16383;
            int j = r & 7, lane = (r >> 3) & 63, ct = (r >> 9) & 7, kc = r >> 12;
            int k = kc * 32 + (lane >> 4) * 8 + j;
            int n = ct * 16 + (lane & 15);
            const float* W = (w == 0) ? W0 : (w == 1) ? W1 : (w == 2) ? W2 : W3;
            Wf[idx] = f2bf(W[k * NFEAT + n]);
        }
    }
}

// ---------------- aggregation (bf16), dwordx4 gathers ----------------
// wave = 1 node. lane = g*16 + p: group g (0..3) handles edge e+g, chunk p (0..15)
// covers bytes [16p,16p+16) of the 256B row. 2-deep unroll -> 8 edges / 2KB in
// flight per wave as dwordx4 loads (4x fewer, 4x wider requests than dword/lane).
// Cross-group sum via shfl_xor(16,32); group 0 adds self row + stores dwordx4.
__global__ __launch_bounds__(256) void k_aggregate_v4(const short* __restrict__ X,
                                                      const int* __restrict__ rowptr,
                                                      const int* __restrict__ adj,
                                                      short* __restrict__ XA, int N) {
    int tid = threadIdx.x;
    int lane = tid & 63;
    int g = lane >> 4;
    int p = lane & 15;
    int wid = (blockIdx.x * blockDim.x + tid) >> 6;
    if (wid >= N) return;
    const uint4* Xv = (const uint4*)X;  // one row = 16 uint4
    float acc[8];
#pragma unroll
    for (int j = 0; j < 8; j++) acc[j] = 0.f;
    int r0 = rowptr[wid], r1 = rowptr[wid + 1];
    for (int e = r0; e < r1; e += 8) {
        int e0 = e + g, e1 = e + 4 + g;
        uint4 v0 = {0u, 0u, 0u, 0u}, v1 = {0u, 0u, 0u, 0u};
        if (e0 < r1) v0 = Xv[(size_t)adj[e0] * 16 + p];
        if (e1 < r1) v1 = Xv[(size_t)adj[e1] * 16 + p];
        acc2(acc[0], acc[1], v0.x);
        acc2(acc[2], acc[3], v0.y);
        acc2(acc[4], acc[5], v0.z);
        acc2(acc[6], acc[7], v0.w);
        acc2(acc[0], acc[1], v1.x);
        acc2(acc[2], acc[3], v1.y);
        acc2(acc[4], acc[5], v1.z);
        acc2(acc[6], acc[7], v1.w);
    }
#pragma unroll
    for (int j = 0; j < 8; j++) {
        acc[j] += __shfl_xor(acc[j], 16);
        acc[j] += __shfl_xor(acc[j], 32);
    }
    if (g == 0) {
        uint4 sv = Xv[(size_t)wid * 16 + p];
        acc2(acc[0], acc[1], sv.x);
        acc2(acc[2], acc[3], sv.y);
        acc2(acc[4], acc[5], sv.z);
        acc2(acc[6], acc[7], sv.w);
        uint4 o;
        o.x = (unsigned)(unsigned short)f2bf(acc[0]) | ((unsigned)(unsigned short)f2bf(acc[1]) << 16);
        o.y = (unsigned)(unsigned short)f2bf(acc[2]) | ((unsigned)(unsigned short)f2bf(acc[3]) << 16);
        o.z = (unsigned)(unsigned short)f2bf(acc[4]) | ((unsigned)(unsigned short)f2bf(acc[5]) << 16);
        o.w = (unsigned)(unsigned short)f2bf(acc[6]) | ((unsigned)(unsigned short)f2bf(acc[7]) << 16);
        ((uint4*)XA)[(size_t)wid * 16 + p] = o;
    }
}

// ---------------- MFMA GEMM (+optional fused BN col-stats) ----------------
template <bool BN_RELU_IN, bool RELU_OUT, bool STATS>
__global__ __launch_bounds__(256) void k_gemm_mfma(const short* __restrict__ A,
                                                   const short* __restrict__ Wf,
                                                   const float* __restrict__ bias,
                                                   const float* __restrict__ scale,
                                                   const float* __restrict__ shift,
                                                   float* __restrict__ stats,
                                                   short* __restrict__ C, int N) {
    __shared__ float s_sum[NFEAT];
    __shared__ float s_sq[NFEAT];
    int tid = threadIdx.x;
    int wave = tid >> 6, lane = tid & 63;
    int quad = lane >> 4, l16 = lane & 15;
    int row_base = blockIdx.x * 128 + wave * 32;

    if constexpr (STATS) {
        if (tid < NFEAT) { s_sum[tid] = 0.f; s_sq[tid] = 0.f; }
        __syncthreads();
    }

    f32x4 acc[2][8];
#pragma unroll
    for (int i = 0; i < 2; i++)
#pragma unroll
        for (int j = 0; j < 8; j++) acc[i][j] = (f32x4){0.f, 0.f, 0.f, 0.f};

    int r0 = row_base + l16;
    int r1 = r0 + 16;

#pragma unroll
    for (int kc = 0; kc < 4; ++kc) {
        int koff = kc * 32 + quad * 8;
        bf16x8 a0 = {}, a1 = {};
        if (r0 < N) a0 = *(const bf16x8*)(A + (size_t)r0 * NFEAT + koff);
        if (r1 < N) a1 = *(const bf16x8*)(A + (size_t)r1 * NFEAT + koff);
        if constexpr (BN_RELU_IN) {
            float sc[8], sh[8];
            *(float4*)(sc) = *(const float4*)(scale + koff);
            *(float4*)(sc + 4) = *(const float4*)(scale + koff + 4);
            *(float4*)(sh) = *(const float4*)(shift + koff);
            *(float4*)(sh + 4) = *(const float4*)(shift + koff + 4);
#pragma unroll
            for (int j = 0; j < 8; j++) {
                float v = fmaxf(bf2f(a0[j]) * sc[j] + sh[j], 0.f);
                float u = fmaxf(bf2f(a1[j]) * sc[j] + sh[j], 0.f);
                a0[j] = f2bf(v);
                a1[j] = f2bf(u);
            }
        }
        const short* wp = Wf + ((size_t)(kc * 8) * 64 + lane) * 8;
#pragma unroll
        for (int ct = 0; ct < 8; ++ct) {
            bf16x8 b = *(const bf16x8*)(wp + (size_t)ct * 64 * 8);
            acc[0][ct] = __builtin_amdgcn_mfma_f32_16x16x32_bf16(a0, b, acc[0][ct], 0, 0, 0);
            acc[1][ct] = __builtin_amdgcn_mfma_f32_16x16x32_bf16(a1, b, acc[1][ct], 0, 0, 0);
        }
    }

    // C/D layout: col = lane&15, row = quad*4 + reg
#pragma unroll
    for (int ct = 0; ct < 8; ++ct) {
        int col = ct * 16 + l16;
        float bv = bias[col];
        float ls = 0.f, ls2 = 0.f;
#pragma unroll
        for (int rt = 0; rt < 2; ++rt) {
#pragma unroll
            for (int reg = 0; reg < 4; ++reg) {
                int row = row_base + rt * 16 + quad * 4 + reg;
                if (row < N) {
                    float v = acc[rt][ct][reg] + bv;
                    if constexpr (RELU_OUT) v = fmaxf(v, 0.f);
                    C[(size_t)row * NFEAT + col] = f2bf(v);
                    if constexpr (STATS) { ls += v; ls2 += v * v; }
                }
            }
        }
        if constexpr (STATS) {
            atomicAdd(&s_sum[col], ls);
            atomicAdd(&s_sq[col], ls2);
        }
    }

    if constexpr (STATS) {
        __syncthreads();
        if (tid < NFEAT) {
            atomicAdd(&stats[tid], s_sum[tid]);
            atomicAdd(&stats[NFEAT + tid], s_sq[tid]);
        }
    }
}

__global__ void k_bnfinalize(const float* __restrict__ stats, const float* __restrict__ gamma,
                             const float* __restrict__ beta, float* __restrict__ scale,
                             float* __restrict__ shift, int N) {
    int c = threadIdx.x;
    if (c < NFEAT) {
        float mean = stats[c] / (float)N;
        float var = stats[NFEAT + c] / (float)N - mean * mean;
        float inv = rsqrtf(var + BN_EPS);
        float sc = gamma[c] * inv;
        scale[c] = sc;
        shift[c] = beta[c] - mean * sc;
    }
}

// ---------------- node-parallel pooling (batch sorted; per-run register accum) ----------
__global__ __launch_bounds__(256) void k_pool2(const short* __restrict__ H2,
                                               const int* __restrict__ batch,
                                               float* __restrict__ pooled, int N) {
    int t = threadIdx.x;
    int c2 = t & 63;
    int rofs = t >> 6;
    int n0 = blockIdx.x * 128;
    int cur = -1;
    float ax = 0.f, ay = 0.f;
    for (int i = 0; i < 32; ++i) {
        int n = n0 + rofs + i * 4;
        if (n >= N) break;
        int g = batch[n];
        if (g != cur) {
            if (cur >= 0) {
                atomicAdd(&pooled[cur * NFEAT + c2 * 2], ax);
                atomicAdd(&pooled[cur * NFEAT + c2 * 2 + 1], ay);
            }
            cur = g; ax = 0.f; ay = 0.f;
        }
        unsigned v = *(const unsigned*)(H2 + (size_t)n * NFEAT + c2 * 2);
        ax += bf2f((short)(v & 0xffff));
        ay += bf2f((short)(v >> 16));
    }
    if (cur >= 0) {
        atomicAdd(&pooled[cur * NFEAT + c2 * 2], ax);
        atomicAdd(&pooled[cur * NFEAT + c2 * 2 + 1], ay);
    }
}

__global__ void k_final(const float* __restrict__ pooled, const float* __restrict__ Wl,
                        const float* __restrict__ bl, float* __restrict__ out) {
    int idx = blockIdx.x * blockDim.x + threadIdx.x;
    if (idx >= NGRAPHS * TGRAPH) return;
    int g = idx / TGRAPH, t = idx % TGRAPH;
    const float* p = pooled + (size_t)g * NFEAT;
    float acc = bl[t];
#pragma unroll 16
    for (int k = 0; k < NFEAT; ++k) acc += p[k] * Wl[k * TGRAPH + t];
    out[idx] = acc;
}

extern "C" void kernel_launch(void* const* d_in, const int* in_sizes, int n_in,
                              void* d_out, int out_size, void* d_ws, size_t ws_size,
                              hipStream_t stream) {
    const float* x = (const float*)d_in[0];
    const int* ei = (const int*)d_in[1];
    const int* batch = (const int*)d_in[2];
    const float* W1a = (const float*)d_in[3];
    const float* b1a = (const float*)d_in[4];
    const float* g1 = (const float*)d_in[5];
    const float* bt1 = (const float*)d_in[6];
    const float* W1b = (const float*)d_in[7];
    const float* b1b = (const float*)d_in[8];
    const float* W2a = (const float*)d_in[9];
    const float* b2a = (const float*)d_in[10];
    const float* g2 = (const float*)d_in[11];
    const float* bt2 = (const float*)d_in[12];
    const float* W2b = (const float*)d_in[13];
    const float* b2b = (const float*)d_in[14];
    const float* Wl = (const float*)d_in[15];
    const float* bl = (const float*)d_in[16];
    float* out = (float*)d_out;

    int N = in_sizes[2];
    int E = in_sizes[1] / 2;
    int nb = (N + 511) >> 9;
    const int* src = ei;
    const int* dst = ei + E;

    char* ws = (char*)d_ws;
    size_t off = 0;
    auto alloc = [&](size_t bytes) -> void* {
        void* p = ws + off;
        off = (off + bytes + 255) & ~(size_t)255;
        return p;
    };
    short* xbf = (short*)alloc((size_t)N * NFEAT * 2);
    short* ag = (short*)alloc((size_t)N * NFEAT * 2);
    short* ybf = (short*)alloc((size_t)N * NFEAT * 2);
    short* hbf = (short*)alloc((size_t)N * NFEAT * 2);
    short* h2bf = (short*)alloc((size_t)N * NFEAT * 2);
    short* Wf = (short*)alloc((size_t)4 * 16384 * 2);
    int* adj = (int*)alloc((size_t)E * 4);
    int2* binned = (int2*)alloc((size_t)E * 8);
    int* rowptr = (int*)alloc((size_t)(N + 1) * 4);
    int* bbase = (int*)alloc(257 * 4);
    int* cur256 = (int*)alloc(256 * 4);
    float* scale = (float*)alloc(128 * 4);
    float* shift = (float*)alloc(128 * 4);
    int* bhist = (int*)alloc(256 * 4);
    float* stats1 = (float*)alloc(256 * 4);
    float* stats2 = (float*)alloc(256 * 4);
    float* pooled = (float*)alloc((size_t)NGRAPHS * NFEAT * 4);
    size_t zbytes = (char*)(pooled + (size_t)NGRAPHS * NFEAT) - (char*)bhist;

    hipMemsetAsync(bhist, 0, zbytes, stream);

    // ---- CSR build (bucket-local) ----
    k_bucket_hist<<<784, 256, 0, stream>>>(dst, bhist, E);
    k_bucket_scan<<<1, 256, 0, stream>>>(bhist, bbase, cur256, E);
    k_bin_scatter<<<(E + BIN_CHUNK - 1) / BIN_CHUNK, 256, 0, stream>>>(src, dst, cur256, binned, E);
    k_bucket_csr<<<nb, 512, 0, stream>>>(binned, bbase, rowptr, adj, N, E, nb);

    // ---- dtype prep (fused) ----
    int n4 = N * NFEAT / 4;
    int prepTot = n4 + 4 * 16384;
    k_prep<<<(prepTot + 255) / 256, 256, 0, stream>>>(x, xbf, W1a, W1b, W2a, W2b, Wf, n4);

    int gemmBlocks = (N + 127) / 128;
    int aggBlocks = (N + 3) / 4;  // one wave per node, 4 waves per block

    // ---- layer 1 ----
    k_aggregate_v4<<<aggBlocks, 256, 0, stream>>>(xbf, rowptr, adj, ag, N);
    k_gemm_mfma<false, false, true><<<gemmBlocks, 256, 0, stream>>>(ag, Wf + 0 * 16384, b1a, nullptr, nullptr, stats1, ybf, N);
    k_bnfinalize<<<1, 128, 0, stream>>>(stats1, g1, bt1, scale, shift, N);
    k_gemm_mfma<true, true, false><<<gemmBlocks, 256, 0, stream>>>(ybf, Wf + 1 * 16384, b1b, scale, shift, nullptr, hbf, N);

    // ---- layer 2 ----
    k_aggregate_v4<<<aggBlocks, 256, 0, stream>>>(hbf, rowptr, adj, ag, N);
    k_gemm_mfma<false, false, true><<<gemmBlocks, 256, 0, stream>>>(ag, Wf + 2 * 16384, b2a, nullptr, nullptr, stats2, ybf, N);
    k_bnfinalize<<<1, 128, 0, stream>>>(stats2, g2, bt2, scale, shift, N);
    k_gemm_mfma<true, true, false><<<gemmBlocks, 256, 0, stream>>>(ybf, Wf + 3 * 16384, b2b, scale, shift, nullptr, h2bf, N);

    // ---- pooling + classifier ----
    k_pool2<<<(N + 127) / 128, 256, 0, stream>>>(h2bf, batch, pooled, N);
    k_final<<<(NGRAPHS * TGRAPH + 255) / 256, 256, 0, stream>>>(pooled, Wl, bl, out);
}